// Round 1
// baseline (271.769 us; speedup 1.0000x reference)
//
#include <hip/hip_runtime.h>
#include <math.h>

#define N_PTS   1000000
#define CI      10
#define C       64
#define NSEG    30000
#define BN_EPS  1e-3f
#define FROFF   31104      // float index of fragment blob (after starts ints)

// ws layout (floats):
// moments: scalar k at ws[7*k], k<65   (stride-7 floats = 28B -> ~1 line apart;
//          spreads the 1024-block atomic fan-in across ~15 L2 lines)
// g_sum:   channel c at ws[512 + 8*c]  (stride-8 floats = 32B)
// ints at [1024:31024): segment starts
// [FROFF : FROFF+15*256): per-lane fragment blob, 15 items x 64 lanes x 16B
#define MSTR 7
#define GOFF 512
#define GSTR 8

using f32x4 = __attribute__((ext_vector_type(4))) float;
using s16x8 = __attribute__((ext_vector_type(8))) short;

__device__ inline short f2bf(float x) {           // RNE fp32 -> bf16 (weights)
    unsigned u = __float_as_uint(x);
    unsigned r = (u + 0x7fffu + ((u >> 16) & 1u)) >> 16;
    return (short)r;
}
__device__ inline unsigned pack_trunc(float lo, float hi) {  // 2x bf16 truncate
    return (__float_as_uint(hi) & 0xffff0000u) | (__float_as_uint(lo) >> 16);
}
__device__ inline float frcp(float x) { return __builtin_amdgcn_rcpf(x); }
// LDS-only drain: write->read visibility within a wave, does NOT drain vmcnt
__device__ inline void lds_fence() {
    asm volatile("s_waitcnt lgkmcnt(0)" ::: "memory");
}

struct Rows { float2 r0, r1, r2, r3; };

// Kernel 1: colsum[10] + second-moment M[55] of raw inputs. Fused: segment
// starts. v2: 1-deep software prefetch of rows+idx; line-spread atomics.
__global__ void __launch_bounds__(256) k_moments(const float* __restrict__ inp,
                                                 const int* __restrict__ idx,
                                                 float* __restrict__ ws,
                                                 int* __restrict__ starts) {
    const int tid = threadIdx.x;
    const int stride = gridDim.x * blockDim.x;
    float v[65];
#pragma unroll
    for (int k = 0; k < 65; ++k) v[k] = 0.f;

    int p = blockIdx.x * blockDim.x + tid;
    float2 a0, a1, a2, a3, a4;
    int ic = 0, ip = 0;
    auto ld = [&](int qq) {
        const float2* r2 = (const float2*)(inp + (size_t)qq * CI);
        a0 = r2[0]; a1 = r2[1]; a2 = r2[2]; a3 = r2[3]; a4 = r2[4];
        ic = idx[qq]; ip = (qq > 0) ? idx[qq - 1] : ic;
    };
    if (p < N_PTS) ld(p);
    while (p < N_PTS) {
        float r[CI] = {a0.x, a0.y, a1.x, a1.y, a2.x, a2.y, a3.x, a3.y, a4.x, a4.y};
        const int cc = ic, cp = ip, cq = p;
        const int pn = p + stride;
        if (pn < N_PTS) ld(pn);                       // prefetch next point

#pragma unroll
        for (int i = 0; i < CI; ++i) v[i] += r[i];
        int kk = 10;
#pragma unroll
        for (int i = 0; i < CI; ++i)
#pragma unroll
            for (int j = i; j < CI; ++j) { v[kk] = fmaf(r[i], r[j], v[kk]); ++kk; }

        if (cq == 0) starts[0] = 0;
        else if (cp != cc) starts[cc] = cq;
        p = pn;
    }

#pragma unroll
    for (int k = 0; k < 65; ++k) {
#pragma unroll
        for (int off = 32; off >= 1; off >>= 1)
            v[k] += __shfl_xor(v[k], off, 64);
    }
    __shared__ float red[4 * 65];
    const int wv = tid >> 6, ln = tid & 63;
    if (ln == 0) {
#pragma unroll
        for (int k = 0; k < 65; ++k) red[wv * 65 + k] = v[k];
    }
    __syncthreads();
    if (tid < 65)
        atomicAdd(&ws[MSTR * tid],
                  red[tid] + red[65 + tid] + red[130 + tid] + red[195 + tid]);
}

// Kernel 2: per-block BN finalize from the 65 moments (LDS only), then
// g_sum[c] = sum_p relu(x'_pc + b_c) via MFMA linear.
// v2: depth-3 row prefetch ring; line-spread g_sum atomics.
__global__ void __launch_bounds__(256) k_gstats(const float* __restrict__ inp,
                                                const float* __restrict__ W,
                                                const float* __restrict__ gamma,
                                                const float* __restrict__ beta,
                                                float* __restrict__ ws) {
    const int tid  = threadIdx.x;
    const int wv   = tid >> 6;
    const int lane = tid & 63;
    const int m = lane & 15;
    const int q = lane >> 4;

    __shared__ float wp[C * CI];   // W' = a*W
    __shared__ float bsh[C];

    if (tid < C) {
        const int c = tid;
        float w[CI];
#pragma unroll
        for (int i = 0; i < CI; ++i) w[i] = W[c * CI + i];
        const float inv_n = 1.f / (float)N_PTS;

        float mu = 0.f;
#pragma unroll
        for (int i = 0; i < CI; ++i) mu = fmaf(w[i], ws[MSTR * i], mu);
        mu *= inv_n;

        float ex2 = 0.f;
        int kk = 10;
#pragma unroll
        for (int i = 0; i < CI; ++i)
#pragma unroll
            for (int j = i; j < CI; ++j) {
                float mm = ws[MSTR * kk];
                float t = w[i] * w[j] * mm;
                ex2 += (i == j) ? t : 2.f * t;
                ++kk;
            }
        ex2 *= inv_n;

        float var = ex2 - mu * mu;
        float rstd = rsqrtf(var + BN_EPS);
        float a = rstd * gamma[c];
        float b = beta[c] - mu * a;
        bsh[c] = b;
#pragma unroll
        for (int i = 0; i < CI; ++i) wp[c * CI + i] = a * w[i];
    }
    __syncthreads();

    s16x8 wfr[4];
#pragma unroll
    for (int nt = 0; nt < 4; ++nt) {
        s16x8 t;
#pragma unroll
        for (int j = 0; j < 8; ++j) {
            int k = 8 * q + j;
            t[j] = (k < CI) ? f2bf(wp[(nt * 16 + m) * CI + k]) : (short)0;
        }
        wfr[nt] = t;
    }
    float bb[4];
#pragma unroll
    for (int nt = 0; nt < 4; ++nt) bb[nt] = bsh[nt * 16 + m];

    const int wid = blockIdx.x * 4 + wv;
    const int nw  = gridDim.x * 4;
    const int NB  = N_PTS / 16;          // 62500

    auto loadrows = [&](int pb) -> Rows {
        Rows R;
        R.r0 = R.r1 = R.r2 = R.r3 = make_float2(0.f, 0.f);
        const float* row = inp + (size_t)(pb + m) * CI;
        if (q == 0) {
            R.r0 = *(const float2*)(row);     R.r1 = *(const float2*)(row + 2);
            R.r2 = *(const float2*)(row + 4); R.r3 = *(const float2*)(row + 6);
        } else if (q == 1) {
            R.r0 = *(const float2*)(row + 8);
        }
        return R;
    };

    float sm[4] = {0.f, 0.f, 0.f, 0.f};
    const f32x4 zero = {0.f, 0.f, 0.f, 0.f};

    // depth-3 ring: L (compute), A (ready), Bv (in flight)
    Rows A  = loadrows(wid * 16);                 // wid < 4096 << NB always
    Rows Bv = loadrows((wid + nw) * 16);          // wid+nw < 8192 << NB always
    for (int b = wid; b < NB; b += nw) {
        Rows L = A; A = Bv;
        if (b + 2 * nw < NB) Bv = loadrows((b + 2 * nw) * 16);

        union { s16x8 v; unsigned u[4]; } t;
        t.v = s16x8{0, 0, 0, 0, 0, 0, 0, 0};
        if (q < 2) t.u[0] = pack_trunc(L.r0.x, L.r0.y);
        if (q == 0) {
            t.u[1] = pack_trunc(L.r1.x, L.r1.y);
            t.u[2] = pack_trunc(L.r2.x, L.r2.y);
            t.u[3] = pack_trunc(L.r3.x, L.r3.y);
        }

#pragma unroll
        for (int nt = 0; nt < 4; ++nt) {
            f32x4 xt = __builtin_amdgcn_mfma_f32_16x16x32_bf16(t.v, wfr[nt], zero, 0, 0, 0);
#pragma unroll
            for (int r = 0; r < 4; ++r)
                sm[nt] += fmaxf(xt[r] + bb[nt], 0.f);
        }
    }

#pragma unroll
    for (int nt = 0; nt < 4; ++nt) {
        sm[nt] += __shfl_xor(sm[nt], 16, 64);
        sm[nt] += __shfl_xor(sm[nt], 32, 64);
    }
    float S = sm[0];
    if (q == 1) S = sm[1];
    if (q == 2) S = sm[2];
    if (q == 3) S = sm[3];

    __shared__ float red[4 * 64];
    red[wv * 64 + lane] = S;              // lane == channel
    __syncthreads();
    if (tid < 64)
        atomicAdd(&ws[GOFF + GSTR * tid],
                  red[tid] + red[64 + tid] + red[128 + tid] + red[192 + tid]);
}

// Kernel 3: k_prep — BN finalize (lane = channel), fp32 xg, and all per-lane
// fragments for k_main, stored as [item][lane] 16B records.
// items 0..3: wfr[nt]; 4..11: bfr[nt][kc] (idx 4+2nt+kc); 12: bb; 13: d1v; 14: xgv
__global__ void k_prep(const float* __restrict__ W,
                       const float* __restrict__ gamma,
                       const float* __restrict__ beta,
                       const float* __restrict__ dw1,
                       const float* __restrict__ pw1,
                       const float* __restrict__ dw2,
                       const float* __restrict__ pw2,
                       float* __restrict__ ws) {
    const int lane = threadIdx.x;     // 0..63 ; lane == channel c
    const int m = lane & 15, q = lane >> 4;
    const float inv_n = 1.f / (float)N_PTS;

    __shared__ float WP[C * CI];   // W' = a*W
    __shared__ float BSH[C], T[C], XG[C];

    // ---- BN finalize for channel `lane`
    {
        float w[CI];
#pragma unroll
        for (int i = 0; i < CI; ++i) w[i] = W[lane * CI + i];
        float mu = 0.f;
#pragma unroll
        for (int i = 0; i < CI; ++i) mu = fmaf(w[i], ws[MSTR * i], mu);
        mu *= inv_n;
        float ex2 = 0.f;
        int kk = 10;
#pragma unroll
        for (int i = 0; i < CI; ++i)
#pragma unroll
            for (int j = i; j < CI; ++j) {
                float mm = ws[MSTR * kk];
                float t = w[i] * w[j] * mm;
                ex2 += (i == j) ? t : 2.f * t;
                ++kk;
            }
        ex2 *= inv_n;
        float var = ex2 - mu * mu;
        float rstd = rsqrtf(var + BN_EPS);
        float a = rstd * gamma[lane];
        BSH[lane] = beta[lane] - mu * a;
#pragma unroll
        for (int i = 0; i < CI; ++i) WP[lane * CI + i] = a * w[i];
        T[lane] = fmaxf(dw2[lane] * (ws[GOFF + GSTR * lane] * inv_n), 0.f);
    }
    __syncthreads();

    // ---- xg = pw2 @ relu(dw2*g)  (exact fp32)
    {
        float acc = 0.f;
#pragma unroll
        for (int k = 0; k < C; ++k) acc = fmaf(pw2[lane * C + k], T[k], acc);
        XG[lane] = acc;
    }
    __syncthreads();

    float4* FR = (float4*)(ws + FROFF);
    union { float4 f; s16x8 v; } u;

#pragma unroll
    for (int nt = 0; nt < 4; ++nt) {
        s16x8 tt;
#pragma unroll
        for (int j = 0; j < 8; ++j) {
            int k = 8 * q + j;
            tt[j] = (k < CI) ? f2bf(WP[(nt * 16 + m) * CI + k]) : (short)0;
        }
        u.v = tt; FR[nt * 64 + lane] = u.f;
    }
#pragma unroll
    for (int nt = 0; nt < 4; ++nt)
#pragma unroll
        for (int kc = 0; kc < 2; ++kc) {
            const float* src = pw1 + (nt * 16 + m) * C + kc * 32 + q * 8;
            float4 p0 = *(const float4*)src, p1 = *(const float4*)(src + 4);
            s16x8 tt;
            tt[0] = f2bf(p0.x); tt[1] = f2bf(p0.y); tt[2] = f2bf(p0.z); tt[3] = f2bf(p0.w);
            tt[4] = f2bf(p1.x); tt[5] = f2bf(p1.y); tt[6] = f2bf(p1.z); tt[7] = f2bf(p1.w);
            u.v = tt; FR[(4 + nt * 2 + kc) * 64 + lane] = u.f;
        }
    float4 f;
    f.x = BSH[m]; f.y = BSH[16 + m]; f.z = BSH[32 + m]; f.w = BSH[48 + m];
    FR[12 * 64 + lane] = f;
    f.x = dw1[m]; f.y = dw1[16 + m]; f.z = dw1[32 + m]; f.w = dw1[48 + m];
    FR[13 * 64 + lane] = f;
    f.x = XG[m]; f.y = XG[16 + m]; f.z = XG[32 + m]; f.w = XG[48 + m];
    FR[14 * 64 + lane] = f;
}

// Kernel 4: k_main — one wave per 2 contiguous segments.
// v2: 32 points per iteration as TWO interleaved 16-pt pipelines sharing one
// LDS drain (was 2 drains per 16 pts -> now 1 effective per 32 pts: the final
// drain is hidden behind the sigmoid/accumulate VALU work). Two independent
// MFMA/trans chains per iteration double ILP at ~2.25 resident waves/SIMD.
#define LD 68
#define SEGW 2
__global__ void __launch_bounds__(128) k_main(const float* __restrict__ inp,
                                              const float* __restrict__ ws,
                                              const int* __restrict__ starts,
                                              float* __restrict__ out) {
    const int tid  = threadIdx.x;
    const int wv   = tid >> 6;
    const int lane = tid & 63;
    const int m = lane & 15;
    const int q = lane >> 4;
    const f32x4 zero = {0.f, 0.f, 0.f, 0.f};

    const float4* FR = (const float4*)(ws + FROFF);
    union { float4 f; s16x8 v; } u;
    s16x8 wfr[4];
#pragma unroll
    for (int nt = 0; nt < 4; ++nt) { u.f = FR[nt * 64 + lane]; wfr[nt] = u.v; }
    s16x8 bfr[4][2];
#pragma unroll
    for (int nt = 0; nt < 4; ++nt)
#pragma unroll
        for (int kc = 0; kc < 2; ++kc) { u.f = FR[(4 + nt * 2 + kc) * 64 + lane]; bfr[nt][kc] = u.v; }
    const float4 bb4  = FR[12 * 64 + lane];
    const float4 d14  = FR[13 * 64 + lane];
    const float4 xg4  = FR[14 * 64 + lane];
    const float bb[4]  = {bb4.x, bb4.y, bb4.z, bb4.w};
    const float d1v[4] = {d14.x, d14.y, d14.z, d14.w};
    const float xgv[4] = {xg4.x, xg4.y, xg4.z, xg4.w};

    __shared__ float sb[2][2][16 * LD];      // [wave][sub-batch tile]
    float* t0 = sb[wv][0];
    float* t1 = sb[wv][1];

    const int w  = blockIdx.x * 2 + wv;    // 0..14999
    const int s0 = w * SEGW;

    int st1 = starts[s0 + 1];
    int st2 = (s0 + 2 < NSEG) ? starts[s0 + 2] : N_PTS;
    const int start   = starts[s0];
    const int end_all = st2;

    int cur = s0;
    int end_cur = st1;

    float sm[4]  = {0.f, 0.f, 0.f, 0.f};
    float mxv[4] = {-INFINITY, -INFINITY, -INFINITY, -INFINITY};

    auto flushseg = [&](int s) {
#pragma unroll
        for (int nt = 0; nt < 4; ++nt) {
            sm[nt] += __shfl_xor(sm[nt], 16, 64);
            sm[nt] += __shfl_xor(sm[nt], 32, 64);
            mxv[nt] = fmaxf(mxv[nt], __shfl_xor(mxv[nt], 16, 64));
            mxv[nt] = fmaxf(mxv[nt], __shfl_xor(mxv[nt], 32, 64));
        }
        float S = sm[0], M = mxv[0];
        if (q == 1) { S = sm[1]; M = mxv[1]; }
        if (q == 2) { S = sm[2]; M = mxv[2]; }
        if (q == 3) { S = sm[3]; M = mxv[3]; }
        out[(size_t)s * C + lane] = S + M;
#pragma unroll
        for (int nt = 0; nt < 4; ++nt) { sm[nt] = 0.f; mxv[nt] = -INFINITY; }
    };

    auto loadrows = [&](int pb) -> Rows {
        Rows R;
        R.r0 = R.r1 = R.r2 = R.r3 = make_float2(0.f, 0.f);
        const float* row = inp + (size_t)min(pb + m, N_PTS - 1) * CI;
        if (q == 0) {
            R.r0 = *(const float2*)(row);     R.r1 = *(const float2*)(row + 2);
            R.r2 = *(const float2*)(row + 4); R.r3 = *(const float2*)(row + 6);
        } else if (q == 1) {
            R.r0 = *(const float2*)(row + 8);
        }
        return R;
    };

    // ring: A0/A1 = current 32 pts, B0/B1 = next 32 pts (in flight)
    Rows A0 = loadrows(start);
    Rows A1 = (start + 16 < end_all) ? loadrows(start + 16) : A0;
    Rows B0 = (start + 32 < end_all) ? loadrows(start + 32) : A0;
    Rows B1 = (start + 48 < end_all) ? loadrows(start + 48) : A0;

    // stage1: rows -> x' (MFMA1) -> BN+ReLU (xn) -> swish -> LDS tile [pt][ch]
    auto stage1 = [&](const Rows& L, float* __restrict__ tile, float (&xn)[4][4]) {
        union { s16x8 v; unsigned uu[4]; } t;
        t.v = s16x8{0, 0, 0, 0, 0, 0, 0, 0};
        if (q < 2) t.uu[0] = pack_trunc(L.r0.x, L.r0.y);
        if (q == 0) {
            t.uu[1] = pack_trunc(L.r1.x, L.r1.y);
            t.uu[2] = pack_trunc(L.r2.x, L.r2.y);
            t.uu[3] = pack_trunc(L.r3.x, L.r3.y);
        }
#pragma unroll
        for (int nt = 0; nt < 4; ++nt) {
            f32x4 xt = __builtin_amdgcn_mfma_f32_16x16x32_bf16(t.v, wfr[nt], zero, 0, 0, 0);
#pragma unroll
            for (int r = 0; r < 4; ++r) {
                float x = fmaxf(xt[r] + bb[nt], 0.f);
                xn[nt][r] = x;
                float sg = x * d1v[nt];
                float sw = sg * frcp(1.f + __expf(-sg));
                tile[(4 * q + r) * LD + nt * 16 + m] = sw;
            }
        }
    };

    // stage2: LDS tile -> A-frags -> xl (MFMA2) -> wei sigmoid -> xi
    auto stage2 = [&](const float* __restrict__ tile, const float (&xn)[4][4],
                      f32x4 (&xi)[4]) {
        s16x8 av[2];
#pragma unroll
        for (int kc = 0; kc < 2; ++kc) {
            const float* src = &tile[m * LD + kc * 32 + q * 8];
            float4 p0 = *(const float4*)src;
            float4 p1 = *(const float4*)(src + 4);
            union { s16x8 v; unsigned uu[4]; } tt;
            tt.uu[0] = pack_trunc(p0.x, p0.y);
            tt.uu[1] = pack_trunc(p0.z, p0.w);
            tt.uu[2] = pack_trunc(p1.x, p1.y);
            tt.uu[3] = pack_trunc(p1.z, p1.w);
            av[kc] = tt.v;
        }
#pragma unroll
        for (int nt = 0; nt < 4; ++nt) {
            xi[nt] = __builtin_amdgcn_mfma_f32_16x16x32_bf16(av[0], bfr[nt][0], zero, 0, 0, 0);
            xi[nt] = __builtin_amdgcn_mfma_f32_16x16x32_bf16(av[1], bfr[nt][1], xi[nt], 0, 0, 0);
#pragma unroll
            for (int r = 0; r < 4; ++r) {
                float v   = xi[nt][r] + xgv[nt];
                float wei = frcp(1.f + __expf(-v));
                float x   = xn[nt][r];
                xi[nt][r] = fmaf(x, wei, x);
            }
        }
    };

    // segmented accumulate (<=1 boundary per 16-pt window: min seg len 33)
    auto accum = [&](const f32x4 (&xi)[4], int b16) {
        const int nb = min(16, end_all - b16);
        const int fin = b16 + nb;
        if (fin <= end_cur) {
            if (nb == 16) {
#pragma unroll
                for (int nt = 0; nt < 4; ++nt)
#pragma unroll
                    for (int r = 0; r < 4; ++r) {
                        sm[nt] += xi[nt][r];
                        mxv[nt] = fmaxf(mxv[nt], xi[nt][r]);
                    }
            } else {
#pragma unroll
                for (int nt = 0; nt < 4; ++nt)
#pragma unroll
                    for (int r = 0; r < 4; ++r) {
                        bool act = (4 * q + r) < nb;
                        sm[nt] += act ? xi[nt][r] : 0.f;
                        mxv[nt] = fmaxf(mxv[nt], act ? xi[nt][r] : -INFINITY);
                    }
            }
            if (fin == end_cur) { flushseg(cur); ++cur; end_cur = st2; }
        } else {
            const int B = end_cur - b16;   // 1..nb-1
#pragma unroll
            for (int nt = 0; nt < 4; ++nt)
#pragma unroll
                for (int r = 0; r < 4; ++r) {
                    bool act = (4 * q + r) < B;
                    sm[nt] += act ? xi[nt][r] : 0.f;
                    mxv[nt] = fmaxf(mxv[nt], act ? xi[nt][r] : -INFINITY);
                }
            flushseg(cur); ++cur;
#pragma unroll
            for (int nt = 0; nt < 4; ++nt)
#pragma unroll
                for (int r = 0; r < 4; ++r) {
                    int pt = 4 * q + r;
                    bool act = (pt >= B) && (pt < nb);
                    sm[nt] += act ? xi[nt][r] : 0.f;
                    mxv[nt] = fmaxf(mxv[nt], act ? xi[nt][r] : -INFINITY);
                }
            end_cur = st2;
        }
    };

    for (int base = start; base < end_all; base += 32) {
        Rows L0 = A0, L1 = A1;
        A0 = B0; A1 = B1;
        if (base + 64 < end_all) B0 = loadrows(base + 64);
        if (base + 80 < end_all) B1 = loadrows(base + 80);
        const bool two = (base + 16) < end_all;

        float xn0[4][4], xn1[4][4];
        f32x4 xi0[4], xi1[4];

        stage1(L0, t0, xn0);
        if (two) stage1(L1, t1, xn1);
        lds_fence();                       // one write->read drain per 32 pts

        stage2(t0, xn0, xi0);
        if (two) stage2(t1, xn1, xi1);

        accum(xi0, base);
        if (two) accum(xi1, base + 16);
        lds_fence();                       // read drain, hidden behind accum VALU
    }
}

extern "C" void kernel_launch(void* const* d_in, const int* in_sizes, int n_in,
                              void* d_out, int out_size, void* d_ws, size_t ws_size,
                              hipStream_t stream) {
    const float* inp   = (const float*)d_in[0];
    const int*   unq   = (const int*)d_in[1];
    const float* W     = (const float*)d_in[2];
    const float* gamma = (const float*)d_in[3];
    const float* beta  = (const float*)d_in[4];
    const float* dw1   = (const float*)d_in[5];
    const float* pw1   = (const float*)d_in[6];
    const float* dw2   = (const float*)d_in[7];
    const float* pw2   = (const float*)d_in[8];
    float* out = (float*)d_out;
    float* ws  = (float*)d_ws;
    int* starts = (int*)ws + 1024;

    hipMemsetAsync(ws, 0, 1024 * sizeof(float), stream);   // zero accumulators

    k_moments <<<1024, 256, 0, stream>>>(inp, unq, ws, starts);
    k_gstats  <<<1024, 256, 0, stream>>>(inp, W, gamma, beta, ws);
    k_prep    <<<1,    64,  0, stream>>>(W, gamma, beta, dw1, pw1, dw2, pw2, ws);
    k_main    <<<7500, 128, 0, stream>>>(inp, ws, starts, out);
}

// Round 5
// 264.036 us; speedup vs baseline: 1.0293x; 1.0293x over previous
//
#include <hip/hip_runtime.h>
#include <math.h>

#define N_PTS   1000000
#define CI      10
#define C       64
#define NSEG    30000
#define BN_EPS  1e-3f
#define FROFF   31104      // float index of fragment blob (after starts ints)

// ws layout (floats):
// moments: scalar k at ws[7*k], k<65   (stride-7 floats spreads atomic fan-in)
// g_sum:   channel c at ws[512 + 8*c]
// ints at [1024:31024): segment starts
// [FROFF : FROFF+15*256): per-lane fragment blob, 15 items x 64 lanes x 16B
#define MSTR 7
#define GOFF 512
#define GSTR 8

using f32x4 = __attribute__((ext_vector_type(4))) float;
using s16x8 = __attribute__((ext_vector_type(8))) short;

__device__ inline short f2bf(float x) {           // RNE fp32 -> bf16 (weights)
    unsigned u = __float_as_uint(x);
    unsigned r = (u + 0x7fffu + ((u >> 16) & 1u)) >> 16;
    return (short)r;
}
__device__ inline unsigned pack_trunc(float lo, float hi) {  // 2x bf16 truncate
    return (__float_as_uint(hi) & 0xffff0000u) | (__float_as_uint(lo) >> 16);
}
__device__ inline float frcp(float x) { return __builtin_amdgcn_rcpf(x); }
// LDS-only drain: write->read visibility within a wave, does NOT drain vmcnt
__device__ inline void lds_fence() {
    asm volatile("s_waitcnt lgkmcnt(0)" ::: "memory");
}

struct Rows { float2 r0, r1, r2, r3; };

// Kernel 1: colsum[10] + second-moment M[55] of raw inputs. Fused: segment
// starts. 1-deep software prefetch of rows+idx; line-spread atomics.
__global__ void __launch_bounds__(256) k_moments(const float* __restrict__ inp,
                                                 const int* __restrict__ idx,
                                                 float* __restrict__ ws,
                                                 int* __restrict__ starts) {
    const int tid = threadIdx.x;
    const int stride = gridDim.x * blockDim.x;
    float v[65];
#pragma unroll
    for (int k = 0; k < 65; ++k) v[k] = 0.f;

    int p = blockIdx.x * blockDim.x + tid;
    float2 a0, a1, a2, a3, a4;
    int ic = 0, ip = 0;
    auto ld = [&](int qq) {
        const float2* r2 = (const float2*)(inp + (size_t)qq * CI);
        a0 = r2[0]; a1 = r2[1]; a2 = r2[2]; a3 = r2[3]; a4 = r2[4];
        ic = idx[qq]; ip = (qq > 0) ? idx[qq - 1] : ic;
    };
    if (p < N_PTS) ld(p);
    while (p < N_PTS) {
        float r[CI] = {a0.x, a0.y, a1.x, a1.y, a2.x, a2.y, a3.x, a3.y, a4.x, a4.y};
        const int cc = ic, cp = ip, cq = p;
        const int pn = p + stride;
        if (pn < N_PTS) ld(pn);                       // prefetch next point

#pragma unroll
        for (int i = 0; i < CI; ++i) v[i] += r[i];
        int kk = 10;
#pragma unroll
        for (int i = 0; i < CI; ++i)
#pragma unroll
            for (int j = i; j < CI; ++j) { v[kk] = fmaf(r[i], r[j], v[kk]); ++kk; }

        if (cq == 0) starts[0] = 0;
        else if (cp != cc) starts[cc] = cq;
        p = pn;
    }

#pragma unroll
    for (int k = 0; k < 65; ++k) {
#pragma unroll
        for (int off = 32; off >= 1; off >>= 1)
            v[k] += __shfl_xor(v[k], off, 64);
    }
    __shared__ float red[4 * 65];
    const int wv = tid >> 6, ln = tid & 63;
    if (ln == 0) {
#pragma unroll
        for (int k = 0; k < 65; ++k) red[wv * 65 + k] = v[k];
    }
    __syncthreads();
    if (tid < 65)
        atomicAdd(&ws[MSTR * tid],
                  red[tid] + red[65 + tid] + red[130 + tid] + red[195 + tid]);
}

// Kernel 2: per-block BN finalize from the 65 moments (LDS only), then
// g_sum[c] = sum_p relu(x'_pc + b_c) via MFMA linear.
// depth-3 row prefetch ring; line-spread g_sum atomics.
__global__ void __launch_bounds__(256) k_gstats(const float* __restrict__ inp,
                                                const float* __restrict__ W,
                                                const float* __restrict__ gamma,
                                                const float* __restrict__ beta,
                                                float* __restrict__ ws) {
    const int tid  = threadIdx.x;
    const int wv   = tid >> 6;
    const int lane = tid & 63;
    const int m = lane & 15;
    const int q = lane >> 4;

    __shared__ float wp[C * CI];   // W' = a*W
    __shared__ float bsh[C];

    if (tid < C) {
        const int c = tid;
        float w[CI];
#pragma unroll
        for (int i = 0; i < CI; ++i) w[i] = W[c * CI + i];
        const float inv_n = 1.f / (float)N_PTS;

        float mu = 0.f;
#pragma unroll
        for (int i = 0; i < CI; ++i) mu = fmaf(w[i], ws[MSTR * i], mu);
        mu *= inv_n;

        float ex2 = 0.f;
        int kk = 10;
#pragma unroll
        for (int i = 0; i < CI; ++i)
#pragma unroll
            for (int j = i; j < CI; ++j) {
                float mm = ws[MSTR * kk];
                float t = w[i] * w[j] * mm;
                ex2 += (i == j) ? t : 2.f * t;
                ++kk;
            }
        ex2 *= inv_n;

        float var = ex2 - mu * mu;
        float rstd = rsqrtf(var + BN_EPS);
        float a = rstd * gamma[c];
        float b = beta[c] - mu * a;
        bsh[c] = b;
#pragma unroll
        for (int i = 0; i < CI; ++i) wp[c * CI + i] = a * w[i];
    }
    __syncthreads();

    s16x8 wfr[4];
#pragma unroll
    for (int nt = 0; nt < 4; ++nt) {
        s16x8 t;
#pragma unroll
        for (int j = 0; j < 8; ++j) {
            int k = 8 * q + j;
            t[j] = (k < CI) ? f2bf(wp[(nt * 16 + m) * CI + k]) : (short)0;
        }
        wfr[nt] = t;
    }
    float bb[4];
#pragma unroll
    for (int nt = 0; nt < 4; ++nt) bb[nt] = bsh[nt * 16 + m];

    const int wid = blockIdx.x * 4 + wv;
    const int nw  = gridDim.x * 4;
    const int NB  = N_PTS / 16;          // 62500

    auto loadrows = [&](int pb) -> Rows {
        Rows R;
        R.r0 = R.r1 = R.r2 = R.r3 = make_float2(0.f, 0.f);
        const float* row = inp + (size_t)(pb + m) * CI;
        if (q == 0) {
            R.r0 = *(const float2*)(row);     R.r1 = *(const float2*)(row + 2);
            R.r2 = *(const float2*)(row + 4); R.r3 = *(const float2*)(row + 6);
        } else if (q == 1) {
            R.r0 = *(const float2*)(row + 8);
        }
        return R;
    };

    float sm[4] = {0.f, 0.f, 0.f, 0.f};
    const f32x4 zero = {0.f, 0.f, 0.f, 0.f};

    // depth-3 ring: L (compute), A (ready), Bv (in flight)
    Rows A  = loadrows(wid * 16);                 // wid < 4096 << NB always
    Rows Bv = loadrows((wid + nw) * 16);          // wid+nw < 8192 << NB always
    for (int b = wid; b < NB; b += nw) {
        Rows L = A; A = Bv;
        if (b + 2 * nw < NB) Bv = loadrows((b + 2 * nw) * 16);

        union { s16x8 v; unsigned u[4]; } t;
        t.v = s16x8{0, 0, 0, 0, 0, 0, 0, 0};
        if (q < 2) t.u[0] = pack_trunc(L.r0.x, L.r0.y);
        if (q == 0) {
            t.u[1] = pack_trunc(L.r1.x, L.r1.y);
            t.u[2] = pack_trunc(L.r2.x, L.r2.y);
            t.u[3] = pack_trunc(L.r3.x, L.r3.y);
        }

#pragma unroll
        for (int nt = 0; nt < 4; ++nt) {
            f32x4 xt = __builtin_amdgcn_mfma_f32_16x16x32_bf16(t.v, wfr[nt], zero, 0, 0, 0);
#pragma unroll
            for (int r = 0; r < 4; ++r)
                sm[nt] += fmaxf(xt[r] + bb[nt], 0.f);
        }
    }

#pragma unroll
    for (int nt = 0; nt < 4; ++nt) {
        sm[nt] += __shfl_xor(sm[nt], 16, 64);
        sm[nt] += __shfl_xor(sm[nt], 32, 64);
    }
    float S = sm[0];
    if (q == 1) S = sm[1];
    if (q == 2) S = sm[2];
    if (q == 3) S = sm[3];

    __shared__ float red[4 * 64];
    red[wv * 64 + lane] = S;              // lane == channel
    __syncthreads();
    if (tid < 64)
        atomicAdd(&ws[GOFF + GSTR * tid],
                  red[tid] + red[64 + tid] + red[128 + tid] + red[192 + tid]);
}

// Kernel 3: k_prep — BN finalize (lane = channel), fp32 xg, and all per-lane
// fragments for k_main, stored as [item][lane] 16B records.
// items 0..3: wfr[nt]; 4..11: bfr[nt][kc] (idx 4+2nt+kc); 12: bb; 13: d1v; 14: xgv
__global__ void k_prep(const float* __restrict__ W,
                       const float* __restrict__ gamma,
                       const float* __restrict__ beta,
                       const float* __restrict__ dw1,
                       const float* __restrict__ pw1,
                       const float* __restrict__ dw2,
                       const float* __restrict__ pw2,
                       float* __restrict__ ws) {
    const int lane = threadIdx.x;     // 0..63 ; lane == channel c
    const int m = lane & 15, q = lane >> 4;
    const float inv_n = 1.f / (float)N_PTS;

    __shared__ float WP[C * CI];   // W' = a*W
    __shared__ float BSH[C], T[C], XG[C];

    // ---- BN finalize for channel `lane`
    {
        float w[CI];
#pragma unroll
        for (int i = 0; i < CI; ++i) w[i] = W[lane * CI + i];
        float mu = 0.f;
#pragma unroll
        for (int i = 0; i < CI; ++i) mu = fmaf(w[i], ws[MSTR * i], mu);
        mu *= inv_n;
        float ex2 = 0.f;
        int kk = 10;
#pragma unroll
        for (int i = 0; i < CI; ++i)
#pragma unroll
            for (int j = i; j < CI; ++j) {
                float mm = ws[MSTR * kk];
                float t = w[i] * w[j] * mm;
                ex2 += (i == j) ? t : 2.f * t;
                ++kk;
            }
        ex2 *= inv_n;
        float var = ex2 - mu * mu;
        float rstd = rsqrtf(var + BN_EPS);
        float a = rstd * gamma[lane];
        BSH[lane] = beta[lane] - mu * a;
#pragma unroll
        for (int i = 0; i < CI; ++i) WP[lane * CI + i] = a * w[i];
        T[lane] = fmaxf(dw2[lane] * (ws[GOFF + GSTR * lane] * inv_n), 0.f);
    }
    __syncthreads();

    // ---- xg = pw2 @ relu(dw2*g)  (exact fp32)
    {
        float acc = 0.f;
#pragma unroll
        for (int k = 0; k < C; ++k) acc = fmaf(pw2[lane * C + k], T[k], acc);
        XG[lane] = acc;
    }
    __syncthreads();

    float4* FR = (float4*)(ws + FROFF);
    union { float4 f; s16x8 v; } u;

#pragma unroll
    for (int nt = 0; nt < 4; ++nt) {
        s16x8 tt;
#pragma unroll
        for (int j = 0; j < 8; ++j) {
            int k = 8 * q + j;
            tt[j] = (k < CI) ? f2bf(WP[(nt * 16 + m) * CI + k]) : (short)0;
        }
        u.v = tt; FR[nt * 64 + lane] = u.f;
    }
#pragma unroll
    for (int nt = 0; nt < 4; ++nt)
#pragma unroll
        for (int kc = 0; kc < 2; ++kc) {
            const float* src = pw1 + (nt * 16 + m) * C + kc * 32 + q * 8;
            float4 p0 = *(const float4*)src, p1 = *(const float4*)(src + 4);
            s16x8 tt;
            tt[0] = f2bf(p0.x); tt[1] = f2bf(p0.y); tt[2] = f2bf(p0.z); tt[3] = f2bf(p0.w);
            tt[4] = f2bf(p1.x); tt[5] = f2bf(p1.y); tt[6] = f2bf(p1.z); tt[7] = f2bf(p1.w);
            u.v = tt; FR[(4 + nt * 2 + kc) * 64 + lane] = u.f;
        }
    float4 f;
    f.x = BSH[m]; f.y = BSH[16 + m]; f.z = BSH[32 + m]; f.w = BSH[48 + m];
    FR[12 * 64 + lane] = f;
    f.x = dw1[m]; f.y = dw1[16 + m]; f.z = dw1[32 + m]; f.w = dw1[48 + m];
    FR[13 * 64 + lane] = f;
    f.x = XG[m]; f.y = XG[16 + m]; f.z = XG[32 + m]; f.w = XG[48 + m];
    FR[14 * 64 + lane] = f;
}

// ---------------------------------------------------------------------------
// Kernel 4: k_main v3 — one wave per 4 contiguous segments. Single 16-pt
// pipeline (84-VGPR-class profile that measured best) + double-buffered LDS
// tile: ONE lgkmcnt drain per batch instead of two. Batch n writes+reads
// tile[n&1]; its reads are drained by batch n+1's fence, before the tile is
// reused at batch n+2. SEGW=4 halves per-wave fragment-setup overhead; 7500
// waves (~7.3/SIMD) still exceed the ~5-wave VGPR residency cap.
// ---------------------------------------------------------------------------
#define LD 68
#define TILE (16 * LD)
#define SEGW 4
__global__ void __launch_bounds__(128) k_main(const float* __restrict__ inp,
                                              const float* __restrict__ ws,
                                              const int* __restrict__ starts,
                                              float* __restrict__ out) {
    const int tid  = threadIdx.x;
    const int wv   = tid >> 6;
    const int lane = tid & 63;
    const int m = lane & 15;
    const int q = lane >> 4;
    const f32x4 zero = {0.f, 0.f, 0.f, 0.f};

    const float4* FR = (const float4*)(ws + FROFF);
    union { float4 f; s16x8 v; } u;
    s16x8 wfr[4];
#pragma unroll
    for (int nt = 0; nt < 4; ++nt) { u.f = FR[nt * 64 + lane]; wfr[nt] = u.v; }
    s16x8 bfr[4][2];
#pragma unroll
    for (int nt = 0; nt < 4; ++nt)
#pragma unroll
        for (int kc = 0; kc < 2; ++kc) { u.f = FR[(4 + nt * 2 + kc) * 64 + lane]; bfr[nt][kc] = u.v; }
    const float4 bb4  = FR[12 * 64 + lane];
    const float4 d14  = FR[13 * 64 + lane];
    const float4 xg4  = FR[14 * 64 + lane];
    const float bb[4]  = {bb4.x, bb4.y, bb4.z, bb4.w};
    const float d1v[4] = {d14.x, d14.y, d14.z, d14.w};
    const float xgv[4] = {xg4.x, xg4.y, xg4.z, xg4.w};

    __shared__ float sb[2][2 * TILE];        // [wave][double-buffered tile]
    float* const tbase = sb[wv];

    const int w  = blockIdx.x * 2 + wv;    // 0..7499
    const int s0 = w * SEGW;

    const int start = starts[s0];
    int end_cur = starts[s0 + 1];
    int n2 = starts[s0 + 2];
    int n3 = starts[s0 + 3];
    int n4 = (s0 + 4 < NSEG) ? starts[s0 + 4] : N_PTS;
    const int end_all = n4;

    int cur = s0;

    float sm[4]  = {0.f, 0.f, 0.f, 0.f};
    float mxv[4] = {-INFINITY, -INFINITY, -INFINITY, -INFINITY};

    auto flushseg = [&](int s) {
#pragma unroll
        for (int nt = 0; nt < 4; ++nt) {
            sm[nt] += __shfl_xor(sm[nt], 16, 64);
            sm[nt] += __shfl_xor(sm[nt], 32, 64);
            mxv[nt] = fmaxf(mxv[nt], __shfl_xor(mxv[nt], 16, 64));
            mxv[nt] = fmaxf(mxv[nt], __shfl_xor(mxv[nt], 32, 64));
        }
        float S = sm[0], M = mxv[0];
        if (q == 1) { S = sm[1]; M = mxv[1]; }
        if (q == 2) { S = sm[2]; M = mxv[2]; }
        if (q == 3) { S = sm[3]; M = mxv[3]; }
        out[(size_t)s * C + lane] = S + M;
#pragma unroll
        for (int nt = 0; nt < 4; ++nt) { sm[nt] = 0.f; mxv[nt] = -INFINITY; }
    };

    auto advance = [&]() {   // pop next segment end off the shift queue
        end_cur = n2; n2 = n3; n3 = n4;
    };

    auto loadrows = [&](int pb) -> Rows {
        Rows R;
        R.r0 = R.r1 = R.r2 = R.r3 = make_float2(0.f, 0.f);
        const float* row = inp + (size_t)min(pb + m, N_PTS - 1) * CI;
        if (q == 0) {
            R.r0 = *(const float2*)(row);     R.r1 = *(const float2*)(row + 2);
            R.r2 = *(const float2*)(row + 4); R.r3 = *(const float2*)(row + 6);
        } else if (q == 1) {
            R.r0 = *(const float2*)(row + 8);
        }
        return R;
    };

    Rows A = loadrows(start);
    Rows B = (start + 16 < end_all) ? loadrows(start + 16) : A;

    int tog = 0;
    for (int base = start; base < end_all; base += 16, tog ^= 1) {
        float* const my = tbase + tog * TILE;
        Rows L = A;
        A = B;
        if (base + 32 < end_all) B = loadrows(base + 32);

        const int nb = min(16, end_all - base);

        // ---- A-frag of rows (K padded to 32, truncation pack)
        union { s16x8 v; unsigned uu[4]; } t;
        t.v = s16x8{0, 0, 0, 0, 0, 0, 0, 0};
        if (q < 2) t.uu[0] = pack_trunc(L.r0.x, L.r0.y);
        if (q == 0) {
            t.uu[1] = pack_trunc(L.r1.x, L.r1.y);
            t.uu[2] = pack_trunc(L.r2.x, L.r2.y);
            t.uu[3] = pack_trunc(L.r3.x, L.r3.y);
        }

        // ---- x' = rows @ W'^T  (C-layout: ch=16nt+m, pt=4q+r)
        f32x4 xt[4];
#pragma unroll
        for (int nt = 0; nt < 4; ++nt)
            xt[nt] = __builtin_amdgcn_mfma_f32_16x16x32_bf16(t.v, wfr[nt], zero, 0, 0, 0);

        // ---- BN + ReLU + swish; sw -> LDS tile [pt][ch]
        float xn[4][4];
#pragma unroll
        for (int nt = 0; nt < 4; ++nt)
#pragma unroll
            for (int r = 0; r < 4; ++r) {
                float x = fmaxf(xt[nt][r] + bb[nt], 0.f);
                xn[nt][r] = x;
                float sg = x * d1v[nt];
                float sw = sg * frcp(1.f + __expf(-sg));
                my[(4 * q + r) * LD + nt * 16 + m] = sw;
            }
        lds_fence();   // drains this tile's writes (RAW) and the OTHER tile's
                       // reads from last batch (WAR for batch n+2's overwrite)

        // ---- A-frags of sw: lane(m,q) reads sw[pt=m][32kc+8q+j]
        s16x8 av[2];
#pragma unroll
        for (int kc = 0; kc < 2; ++kc) {
            const float* src = &my[m * LD + kc * 32 + q * 8];
            float4 p0 = *(const float4*)src;
            float4 p1 = *(const float4*)(src + 4);
            union { s16x8 v; unsigned uu[4]; } tt;
            tt.uu[0] = pack_trunc(p0.x, p0.y);
            tt.uu[1] = pack_trunc(p0.z, p0.w);
            tt.uu[2] = pack_trunc(p1.x, p1.y);
            tt.uu[3] = pack_trunc(p1.z, p1.w);
            av[kc] = tt.v;
        }

        // ---- xl = sw @ pw1^T (C-layout, aligned with xn)
        f32x4 xi[4];
#pragma unroll
        for (int nt = 0; nt < 4; ++nt) {
            xi[nt] = __builtin_amdgcn_mfma_f32_16x16x32_bf16(av[0], bfr[nt][0], zero, 0, 0, 0);
            xi[nt] = __builtin_amdgcn_mfma_f32_16x16x32_bf16(av[1], bfr[nt][1], xi[nt], 0, 0, 0);
        }

#pragma unroll
        for (int nt = 0; nt < 4; ++nt)
#pragma unroll
            for (int r = 0; r < 4; ++r) {
                float v   = xi[nt][r] + xgv[nt];
                float wei = frcp(1.f + __expf(-v));
                float x   = xn[nt][r];
                xi[nt][r] = fmaf(x, wei, x);
            }

        // ---- segmented accumulate (<=1 boundary per batch: min seg len 33)
        const int fin = base + nb;
        if (fin <= end_cur) {
            if (nb == 16) {
#pragma unroll
                for (int nt = 0; nt < 4; ++nt)
#pragma unroll
                    for (int r = 0; r < 4; ++r) {
                        sm[nt] += xi[nt][r];
                        mxv[nt] = fmaxf(mxv[nt], xi[nt][r]);
                    }
            } else {
#pragma unroll
                for (int nt = 0; nt < 4; ++nt)
#pragma unroll
                    for (int r = 0; r < 4; ++r) {
                        bool act = (4 * q + r) < nb;
                        sm[nt] += act ? xi[nt][r] : 0.f;
                        mxv[nt] = fmaxf(mxv[nt], act ? xi[nt][r] : -INFINITY);
                    }
            }
            if (fin == end_cur) { flushseg(cur); ++cur; advance(); }
        } else {
            const int Bn = end_cur - base;   // 1..nb-1
#pragma unroll
            for (int nt = 0; nt < 4; ++nt)
#pragma unroll
                for (int r = 0; r < 4; ++r) {
                    bool act = (4 * q + r) < Bn;
                    sm[nt] += act ? xi[nt][r] : 0.f;
                    mxv[nt] = fmaxf(mxv[nt], act ? xi[nt][r] : -INFINITY);
                }
            flushseg(cur); ++cur;
#pragma unroll
            for (int nt = 0; nt < 4; ++nt)
#pragma unroll
                for (int r = 0; r < 4; ++r) {
                    int pt = 4 * q + r;
                    bool act = (pt >= Bn) && (pt < nb);
                    sm[nt] += act ? xi[nt][r] : 0.f;
                    mxv[nt] = fmaxf(mxv[nt], act ? xi[nt][r] : -INFINITY);
                }
            advance();
        }
    }
}

extern "C" void kernel_launch(void* const* d_in, const int* in_sizes, int n_in,
                              void* d_out, int out_size, void* d_ws, size_t ws_size,
                              hipStream_t stream) {
    const float* inp   = (const float*)d_in[0];
    const int*   unq   = (const int*)d_in[1];
    const float* W     = (const float*)d_in[2];
    const float* gamma = (const float*)d_in[3];
    const float* beta  = (const float*)d_in[4];
    const float* dw1   = (const float*)d_in[5];
    const float* pw1   = (const float*)d_in[6];
    const float* dw2   = (const float*)d_in[7];
    const float* pw2   = (const float*)d_in[8];
    float* out = (float*)d_out;
    float* ws  = (float*)d_ws;
    int* starts = (int*)ws + 1024;

    hipMemsetAsync(ws, 0, 1024 * sizeof(float), stream);   // zero accumulators

    k_moments <<<1024, 256, 0, stream>>>(inp, unq, ws, starts);
    k_gstats  <<<1024, 256, 0, stream>>>(inp, W, gamma, beta, ws);
    k_prep    <<<1,    64,  0, stream>>>(W, gamma, beta, dw1, pw1, dw2, pw2, ws);
    k_main    <<<3750, 128, 0, stream>>>(inp, ws, starts, out);
}